// Round 1
// baseline (391.249 us; speedup 1.0000x reference)
//
#include <hip/hip_runtime.h>
#include <stdint.h>

#define SEQ   512
#define NB    1024
#define NIN   64
#define NH    16
#define NCLS  6

typedef __attribute__((ext_vector_type(8))) short short8;
typedef __attribute__((ext_vector_type(4))) float f32x4;

__device__ __forceinline__ float sigfast(float z) {
    // sigma(z) = 1 / (1 + 2^(-z*log2e))
    return __builtin_amdgcn_rcpf(1.f + __builtin_amdgcn_exp2f(z * -1.4426950408889634f));
}

__device__ __forceinline__ float readlane_f(float v, int l) {
    return __int_as_float(__builtin_amdgcn_readlane(__float_as_int(v), l));
}

// Split fp32 -> bf16 hi + bf16 lo (truncation split; residual ~2^-16 relative)
__device__ __forceinline__ void split8(float4 u0, float4 u1, short8& hi, short8& lo) {
    float f[8] = {u0.x, u0.y, u0.z, u0.w, u1.x, u1.y, u1.z, u1.w};
    #pragma unroll
    for (int j = 0; j < 8; ++j) {
        uint32_t b = __float_as_uint(f[j]);
        uint16_t hb = (uint16_t)(b >> 16);
        hi[j] = (short)hb;
        float hf = __uint_as_float(((uint32_t)hb) << 16);
        lo[j] = (short)(uint16_t)(__float_as_uint(f[j] - hf) >> 16);
    }
}

__global__ __launch_bounds__(256, 1)
void lstm_fused_kernel(const float* __restrict__ x,
                       const float* __restrict__ w_ih,
                       const float* __restrict__ w_hh,
                       const float* __restrict__ b_ih,
                       const float* __restrict__ b_hh,
                       const float* __restrict__ w_fc,
                       const float* __restrict__ b_fc,
                       float* __restrict__ out)
{
    __shared__ float stage[4][16 * 65];   // per-wave gate staging, pad 65

    const int tid  = threadIdx.x;
    const int wid  = tid >> 6;
    const int lane = tid & 63;
    const int b    = blockIdx.x * 4 + wid;

    const int ml = lane & 15;          // A row (timestep) / B col (gate-in-tile)
    const int kk = (lane >> 4) * 8;    // k-chunk base within K=32

    // ---- preload w_ih B fragments (4 gate tiles x 2 K-chunks, hi/lo split) ----
    short8 Bh[4][2], Bl[4][2];
    #pragma unroll
    for (int tau = 0; tau < 4; ++tau) {
        #pragma unroll
        for (int ch = 0; ch < 2; ++ch) {
            const float* wr = w_ih + (tau * 16 + ml) * NIN + ch * 32 + kk;
            float4 u0 = *(const float4*)wr;
            float4 u1 = *(const float4*)(wr + 4);
            split8(u0, u1, Bh[tau][ch], Bl[tau][ch]);
        }
    }

    // ---- per-lane recurrent weights / bias (lane g = gate index 0..63) ----
    float whh[NH];
    #pragma unroll
    for (int j = 0; j < NH; j += 4) {
        float4 u = *(const float4*)(w_hh + lane * NH + j);
        whh[j] = u.x; whh[j+1] = u.y; whh[j+2] = u.z; whh[j+3] = u.w;
    }
    const float bias = b_ih[lane] + b_hh[lane];

    // unified activation: act = sA * sigma(sA * g) + sB   (tanh = 2*sigma(2x)-1)
    const bool isg  = (lane >= 32) && (lane < 48);
    const float sA  = isg ? 2.f : 1.f;
    const float sB  = isg ? -1.f : 0.f;

    // ---- state ----
    float c_state = 0.f;
    float hs[NH];
    #pragma unroll
    for (int j = 0; j < NH; ++j) hs[j] = 0.f;
    float accfc[NCLS];
    #pragma unroll
    for (int cls = 0; cls < NCLS; ++cls) accfc[cls] = 0.f;

    // ---- prefetch first x group ----
    const float* xbase = x + ((size_t)b * SEQ + ml) * NIN + kk;
    float4 px0 = *(const float4*)(xbase + 0);
    float4 px1 = *(const float4*)(xbase + 4);
    float4 px2 = *(const float4*)(xbase + 32);
    float4 px3 = *(const float4*)(xbase + 36);

    for (int grp = 0; grp < SEQ / 16; ++grp) {
        // convert current group's x to MFMA A fragments (hi/lo)
        short8 a0h, a0l, a1h, a1l;
        split8(px0, px1, a0h, a0l);
        split8(px2, px3, a1h, a1l);

        // prefetch next group's x
        if (grp < SEQ / 16 - 1) {
            const float* xp = xbase + (size_t)(grp + 1) * 16 * NIN;
            px0 = *(const float4*)(xp + 0);
            px1 = *(const float4*)(xp + 4);
            px2 = *(const float4*)(xp + 32);
            px3 = *(const float4*)(xp + 36);
        }

        // gates_x for 16 timesteps: 4 gate tiles, K=64 in 2 chunks, hi/lo cross terms
        f32x4 acc[4];
        #pragma unroll
        for (int tau = 0; tau < 4; ++tau) {
            f32x4 c_ = {0.f, 0.f, 0.f, 0.f};
            c_ = __builtin_amdgcn_mfma_f32_16x16x32_bf16(a0h, Bh[tau][0], c_, 0, 0, 0);
            c_ = __builtin_amdgcn_mfma_f32_16x16x32_bf16(a1h, Bh[tau][1], c_, 0, 0, 0);
            c_ = __builtin_amdgcn_mfma_f32_16x16x32_bf16(a0l, Bh[tau][0], c_, 0, 0, 0);
            c_ = __builtin_amdgcn_mfma_f32_16x16x32_bf16(a0h, Bl[tau][0], c_, 0, 0, 0);
            c_ = __builtin_amdgcn_mfma_f32_16x16x32_bf16(a1l, Bh[tau][1], c_, 0, 0, 0);
            c_ = __builtin_amdgcn_mfma_f32_16x16x32_bf16(a1h, Bl[tau][1], c_, 0, 0, 0);
            acc[tau] = c_;
        }

        // scatter C (row = local timestep, col = gate) to wave-private LDS
        const int trow = (lane >> 4) * 4;
        #pragma unroll
        for (int tau = 0; tau < 4; ++tau) {
            #pragma unroll
            for (int r = 0; r < 4; ++r) {
                stage[wid][(trow + r) * 65 + tau * 16 + ml] = acc[tau][r];
            }
        }
        __builtin_amdgcn_s_waitcnt(0);  // drain LDS writes before reads (wave-sync)

        // ---- 16 sequential recurrence steps ----
        #pragma unroll 4
        for (int r = 0; r < 16; ++r) {
            const int t = grp * 16 + r;
            const float gv = stage[wid][r * 65 + lane];

            // gate preactivation: gx + bias + sum_j h[j]*w_hh[g][j]  (4 chains)
            float q0 = gv + bias, q1 = 0.f, q2 = 0.f, q3 = 0.f;
            #pragma unroll
            for (int j = 0; j < NH; j += 4) {
                q0 = fmaf(hs[j+0], whh[j+0], q0);
                q1 = fmaf(hs[j+1], whh[j+1], q1);
                q2 = fmaf(hs[j+2], whh[j+2], q2);
                q3 = fmaf(hs[j+3], whh[j+3], q3);
            }
            const float gate = (q0 + q1) + (q2 + q3);

            // activation (sigmoid for i,f,o lanes; tanh for g lanes)
            const float act = fmaf(sA, sigfast(sA * gate), sB);

            // gather f, g', o onto lanes 0..15 (all lanes active for shfl)
            const float fg = __shfl(act, lane + 16);
            const float gg = __shfl(act, lane + 32);
            const float og = __shfl(act, lane + 48);

            float hn = 0.f;
            if (lane < NH) {
                const float* wfp = w_fc + t * NH + lane;
                const float f0 = wfp[0];
                const float f1 = wfp[8192];
                const float f2 = wfp[16384];
                const float f3 = wfp[24576];
                const float f4 = wfp[32768];
                const float f5 = wfp[40960];

                c_state = fmaf(fg, c_state, act * gg);
                const float th = fmaf(2.f, sigfast(2.f * c_state), -1.f);
                hn = og * th;

                accfc[0] = fmaf(hn, f0, accfc[0]);
                accfc[1] = fmaf(hn, f1, accfc[1]);
                accfc[2] = fmaf(hn, f2, accfc[2]);
                accfc[3] = fmaf(hn, f3, accfc[3]);
                accfc[4] = fmaf(hn, f4, accfc[4]);
                accfc[5] = fmaf(hn, f5, accfc[5]);
            }

            // broadcast new h to all lanes as wave-uniform scalars (SGPRs)
            #pragma unroll
            for (int j = 0; j < NH; ++j) hs[j] = readlane_f(hn, j);
        }
    }

    // ---- reduce FC accumulators over lanes 0..15 and store ----
    #pragma unroll
    for (int cls = 0; cls < NCLS; ++cls) {
        float v = accfc[cls];
        v += __shfl_xor(v, 1);
        v += __shfl_xor(v, 2);
        v += __shfl_xor(v, 4);
        v += __shfl_xor(v, 8);
        accfc[cls] = v;
    }
    if (lane == 0) {
        #pragma unroll
        for (int cls = 0; cls < NCLS; ++cls)
            out[b * NCLS + cls] = accfc[cls] + b_fc[cls];
    }
}

extern "C" void kernel_launch(void* const* d_in, const int* in_sizes, int n_in,
                              void* d_out, int out_size, void* d_ws, size_t ws_size,
                              hipStream_t stream) {
    const float* x    = (const float*)d_in[0];
    const float* w_ih = (const float*)d_in[1];
    const float* w_hh = (const float*)d_in[2];
    const float* b_ih = (const float*)d_in[3];
    const float* b_hh = (const float*)d_in[4];
    const float* w_fc = (const float*)d_in[5];
    const float* b_fc = (const float*)d_in[6];
    float* out = (float*)d_out;

    hipLaunchKernelGGL(lstm_fused_kernel, dim3(NB / 4), dim3(256), 0, stream,
                       x, w_ih, w_hh, b_ih, b_hh, w_fc, b_fc, out);
}

// Round 2
// 255.544 us; speedup vs baseline: 1.5310x; 1.5310x over previous
//
#include <hip/hip_runtime.h>
#include <stdint.h>

#define SEQ   512
#define NB    1024
#define NIN   64
#define NH    16
#define NCLS  6

typedef __attribute__((ext_vector_type(8))) short short8;
typedef __attribute__((ext_vector_type(4))) float f32x4;

__device__ __forceinline__ float sigfast(float z) {
    // sigma(z) = 1 / (1 + 2^(-z*log2e))
    return __builtin_amdgcn_rcpf(1.f + __builtin_amdgcn_exp2f(z * -1.4426950408889634f));
}

__device__ __forceinline__ float readlane_f(float v, int l) {
    return __int_as_float(__builtin_amdgcn_readlane(__float_as_int(v), l));
}

// Split fp32 -> bf16 hi + bf16 lo (truncation split; residual ~2^-16 relative)
__device__ __forceinline__ void split8(float4 u0, float4 u1, short8& hi, short8& lo) {
    float f[8] = {u0.x, u0.y, u0.z, u0.w, u1.x, u1.y, u1.z, u1.w};
    #pragma unroll
    for (int j = 0; j < 8; ++j) {
        uint32_t b = __float_as_uint(f[j]);
        uint16_t hb = (uint16_t)(b >> 16);
        hi[j] = (short)hb;
        float hf = __uint_as_float(((uint32_t)hb) << 16);
        lo[j] = (short)(uint16_t)(__float_as_uint(f[j] - hf) >> 16);
    }
}

#define GSTRIDE 20   // floats per gate row in LDS (16 data + 4 pad, keeps 16B align)

__global__ __launch_bounds__(256, 1)
void lstm_fused_kernel(const float* __restrict__ x,
                       const float* __restrict__ w_ih,
                       const float* __restrict__ w_hh,
                       const float* __restrict__ b_ih,
                       const float* __restrict__ b_hh,
                       const float* __restrict__ w_fc,
                       const float* __restrict__ b_fc,
                       float* __restrict__ out)
{
    __shared__ float stageG[4][64 * GSTRIDE];  // gate-major staged gates_x
    __shared__ float stageHT[4][256];          // h history, flat t*16+j

    const int tid  = threadIdx.x;
    const int wid  = tid >> 6;
    const int lane = tid & 63;
    const int b    = blockIdx.x * 4 + wid;

    const int ml   = lane & 15;        // A row (timestep) / B col (gate-in-tile)
    const int half = lane >> 4;        // 0..3
    const int kk   = half * 8;         // k-chunk base within K=32

    // ---- preload w_ih B fragments (4 gate tiles x 2 K-chunks, hi/lo split) ----
    short8 Bh[4][2], Bl[4][2];
    #pragma unroll
    for (int tau = 0; tau < 4; ++tau) {
        #pragma unroll
        for (int ch = 0; ch < 2; ++ch) {
            const float* wr = w_ih + (tau * 16 + ml) * NIN + ch * 32 + kk;
            float4 u0 = *(const float4*)wr;
            float4 u1 = *(const float4*)(wr + 4);
            split8(u0, u1, Bh[tau][ch], Bl[tau][ch]);
        }
    }

    // ---- per-lane recurrent weights / bias (lane g = gate index 0..63) ----
    float whh[NH];
    #pragma unroll
    for (int j = 0; j < NH; j += 4) {
        float4 u = *(const float4*)(w_hh + lane * NH + j);
        whh[j] = u.x; whh[j+1] = u.y; whh[j+2] = u.z; whh[j+3] = u.w;
    }
    const float bias = b_ih[lane] + b_hh[lane];

    // unified activation: act = sA * sigma(sA * g) + sB   (tanh = 2*sigma(2x)-1)
    const bool isg  = (lane >= 32) && (lane < 48);
    const float sA  = isg ? 2.f : 1.f;
    const float sB  = isg ? -1.f : 0.f;

    // ---- state (c/h replicated across all 4 lane-quadrants) ----
    float c_state = 0.f;
    float hs[NH];
    #pragma unroll
    for (int j = 0; j < NH; ++j) hs[j] = 0.f;
    float accfc[NCLS];
    #pragma unroll
    for (int cls = 0; cls < NCLS; ++cls) accfc[cls] = 0.f;

    // ---- prefetch first x group ----
    const float* xbase = x + ((size_t)b * SEQ + ml) * NIN + kk;
    float4 px0 = *(const float4*)(xbase + 0);
    float4 px1 = *(const float4*)(xbase + 4);
    float4 px2 = *(const float4*)(xbase + 32);
    float4 px3 = *(const float4*)(xbase + 36);

    const int u = lane & 15;  // hidden-unit this lane tracks for c/h

    for (int grp = 0; grp < SEQ / 16; ++grp) {
        // w_fc chunk for this group's FC partial (consumed at group end -> hidden)
        float4 wf[NCLS];
        #pragma unroll
        for (int cls = 0; cls < NCLS; ++cls)
            wf[cls] = *(const float4*)(w_fc + cls * (SEQ * NH) + grp * 256 + lane * 4);

        // convert current group's x to MFMA A fragments (hi/lo)
        short8 a0h, a0l, a1h, a1l;
        split8(px0, px1, a0h, a0l);
        split8(px2, px3, a1h, a1l);

        // prefetch next group's x
        if (grp < SEQ / 16 - 1) {
            const float* xp = xbase + (size_t)(grp + 1) * 16 * NIN;
            px0 = *(const float4*)(xp + 0);
            px1 = *(const float4*)(xp + 4);
            px2 = *(const float4*)(xp + 32);
            px3 = *(const float4*)(xp + 36);
        }

        // gates_x for 16 timesteps: 4 gate tiles, K=64 in 2 chunks, hi/lo cross terms
        f32x4 acc[4];
        #pragma unroll
        for (int tau = 0; tau < 4; ++tau) {
            f32x4 c_ = {0.f, 0.f, 0.f, 0.f};
            c_ = __builtin_amdgcn_mfma_f32_16x16x32_bf16(a0h, Bh[tau][0], c_, 0, 0, 0);
            c_ = __builtin_amdgcn_mfma_f32_16x16x32_bf16(a1h, Bh[tau][1], c_, 0, 0, 0);
            c_ = __builtin_amdgcn_mfma_f32_16x16x32_bf16(a0l, Bh[tau][0], c_, 0, 0, 0);
            c_ = __builtin_amdgcn_mfma_f32_16x16x32_bf16(a0h, Bl[tau][0], c_, 0, 0, 0);
            c_ = __builtin_amdgcn_mfma_f32_16x16x32_bf16(a1l, Bh[tau][1], c_, 0, 0, 0);
            c_ = __builtin_amdgcn_mfma_f32_16x16x32_bf16(a1h, Bl[tau][1], c_, 0, 0, 0);
            acc[tau] = c_;
        }

        // scatter C to gate-major LDS: row gate=tau*16+ml, 4 consecutive t (b128)
        #pragma unroll
        for (int tau = 0; tau < 4; ++tau) {
            *(f32x4*)&stageG[wid][(tau * 16 + ml) * GSTRIDE + half * 4] = acc[tau];
        }
        __builtin_amdgcn_s_waitcnt(0xC07F);  // lgkmcnt(0) only; vmcnt untouched

        // each lane loads its own gate's 16-step row (vector, once per group)
        float gvv[16];
        #pragma unroll
        for (int q = 0; q < 4; ++q) {
            f32x4 g4 = *(f32x4*)&stageG[wid][lane * GSTRIDE + q * 4];
            gvv[q*4+0] = g4[0]; gvv[q*4+1] = g4[1]; gvv[q*4+2] = g4[2]; gvv[q*4+3] = g4[3];
        }

        // ---- 16 sequential recurrence steps (zero memory ops on the chain) ----
        #pragma unroll
        for (int r = 0; r < 16; ++r) {
            float q0 = fmaf(hs[0], whh[0], gvv[r] + bias);
            float q1 = hs[1] * whh[1];
            float q2 = hs[2] * whh[2];
            float q3 = hs[3] * whh[3];
            #pragma unroll
            for (int j = 4; j < NH; j += 4) {
                q0 = fmaf(hs[j+0], whh[j+0], q0);
                q1 = fmaf(hs[j+1], whh[j+1], q1);
                q2 = fmaf(hs[j+2], whh[j+2], q2);
                q3 = fmaf(hs[j+3], whh[j+3], q3);
            }
            const float gate = (q0 + q1) + (q2 + q3);

            // activation (sigmoid for i,f,o lanes; tanh for g lanes)
            const float act = fmaf(sA, sigfast(sA * gate), sB);

            // gather i,f,g,o for unit u onto every lane (4 independent bpermutes)
            const float ig = __shfl(act, u);
            const float fg = __shfl(act, u + 16);
            const float gg = __shfl(act, u + 32);
            const float og = __shfl(act, u + 48);

            c_state = fmaf(fg, c_state, ig * gg);
            const float th = fmaf(2.f, sigfast(2.f * c_state), -1.f);
            const float hn = og * th;

            if (lane < NH) stageHT[wid][r * NH + lane] = hn;

            // broadcast new h as wave-uniform scalars (SGPRs)
            #pragma unroll
            for (int j = 0; j < NH; ++j) hs[j] = readlane_f(hn, j);
        }
        __builtin_amdgcn_s_waitcnt(0xC07F);  // hist writes visible

        // ---- FC partial for this group: all 64 lanes, coalesced ----
        {
            float4 h4 = *(float4*)&stageHT[wid][lane * 4];
            #pragma unroll
            for (int cls = 0; cls < NCLS; ++cls) {
                accfc[cls] = fmaf(h4.x, wf[cls].x, accfc[cls]);
                accfc[cls] = fmaf(h4.y, wf[cls].y, accfc[cls]);
                accfc[cls] = fmaf(h4.z, wf[cls].z, accfc[cls]);
                accfc[cls] = fmaf(h4.w, wf[cls].w, accfc[cls]);
            }
        }
    }

    // ---- reduce FC accumulators over all 64 lanes and store ----
    #pragma unroll
    for (int cls = 0; cls < NCLS; ++cls) {
        float v = accfc[cls];
        v += __shfl_xor(v, 1);
        v += __shfl_xor(v, 2);
        v += __shfl_xor(v, 4);
        v += __shfl_xor(v, 8);
        v += __shfl_xor(v, 16);
        v += __shfl_xor(v, 32);
        accfc[cls] = v;
    }
    if (lane == 0) {
        #pragma unroll
        for (int cls = 0; cls < NCLS; ++cls)
            out[b * NCLS + cls] = accfc[cls] + b_fc[cls];
    }
}

extern "C" void kernel_launch(void* const* d_in, const int* in_sizes, int n_in,
                              void* d_out, int out_size, void* d_ws, size_t ws_size,
                              hipStream_t stream) {
    const float* x    = (const float*)d_in[0];
    const float* w_ih = (const float*)d_in[1];
    const float* w_hh = (const float*)d_in[2];
    const float* b_ih = (const float*)d_in[3];
    const float* b_hh = (const float*)d_in[4];
    const float* w_fc = (const float*)d_in[5];
    const float* b_fc = (const float*)d_in[6];
    float* out = (float*)d_out;

    hipLaunchKernelGGL(lstm_fused_kernel, dim3(NB / 4), dim3(256), 0, stream,
                       x, w_ih, w_hh, b_ih, b_hh, w_fc, b_fc, out);
}

// Round 4
// 239.178 us; speedup vs baseline: 1.6358x; 1.0684x over previous
//
#include <hip/hip_runtime.h>
#include <stdint.h>

#define SEQ   512
#define NB    1024
#define NIN   64
#define NH    16
#define NCLS  6
#define GSTRIDE 20   // floats per gate row in LDS (16 data + 4 pad, bank-balanced)

typedef __attribute__((ext_vector_type(8))) short short8;
typedef __attribute__((ext_vector_type(4))) float f32x4;

__device__ __forceinline__ float readlane_f(float v, int l) {
    return __int_as_float(__builtin_amdgcn_readlane(__float_as_int(v), l));
}

// Split fp32 -> bf16 hi + bf16 lo (truncation split; residual ~2^-16 relative)
// R2-proven shift-based version.
__device__ __forceinline__ void split8(float4 u0, float4 u1, short8& hi, short8& lo) {
    float f[8] = {u0.x, u0.y, u0.z, u0.w, u1.x, u1.y, u1.z, u1.w};
    #pragma unroll
    for (int j = 0; j < 8; ++j) {
        uint32_t b = __float_as_uint(f[j]);
        uint16_t hb = (uint16_t)(b >> 16);
        hi[j] = (short)hb;
        float hf = __uint_as_float(((uint32_t)hb) << 16);
        lo[j] = (short)(uint16_t)(__float_as_uint(f[j] - hf) >> 16);
    }
}

// quad_perm broadcast via the rocPRIM-standard update_dpp builtin (VALU-latency)
__device__ __forceinline__ float quad_bcast0(float v) {
    return __int_as_float(__builtin_amdgcn_update_dpp(0, __float_as_int(v), 0x00, 0xF, 0xF, true));
}
__device__ __forceinline__ float quad_bcast1(float v) {
    return __int_as_float(__builtin_amdgcn_update_dpp(0, __float_as_int(v), 0x55, 0xF, 0xF, true));
}
__device__ __forceinline__ float quad_bcast2(float v) {
    return __int_as_float(__builtin_amdgcn_update_dpp(0, __float_as_int(v), 0xAA, 0xF, 0xF, true));
}
__device__ __forceinline__ float quad_bcast3(float v) {
    return __int_as_float(__builtin_amdgcn_update_dpp(0, __float_as_int(v), 0xFF, 0xF, 0xF, true));
}

__global__ __launch_bounds__(256, 1)
void lstm_fused_kernel(const float* __restrict__ x,
                       const float* __restrict__ w_ih,
                       const float* __restrict__ w_hh,
                       const float* __restrict__ b_ih,
                       const float* __restrict__ b_hh,
                       const float* __restrict__ w_fc,
                       const float* __restrict__ b_fc,
                       float* __restrict__ out)
{
    __shared__ float stageG[4][64 * GSTRIDE];  // unit-major staged gates_x (+bias)
    __shared__ float stageHT[4][256];          // h history, flat t*16+j

    const int tid  = threadIdx.x;
    const int wid  = tid >> 6;
    const int lane = tid & 63;
    const int b    = blockIdx.x * 4 + wid;

    const int ml   = lane & 15;        // MFMA A row (timestep) / B col (unit)
    const int half = lane >> 4;        // 0..3
    const int kk   = half * 8;         // k-chunk base within K=32

    // ---- preload w_ih B fragments (4 gate tiles x 2 K-chunks, hi/lo split) ----
    short8 Bh[4][2], Bl[4][2];
    #pragma unroll
    for (int tau = 0; tau < 4; ++tau) {
        #pragma unroll
        for (int ch = 0; ch < 2; ++ch) {
            const float* wr = w_ih + (tau * 16 + ml) * NIN + ch * 32 + kk;
            float4 u0 = *(const float4*)wr;
            float4 u1 = *(const float4*)(wr + 4);
            split8(u0, u1, Bh[tau][ch], Bl[tau][ch]);
        }
    }

    // bias for staging-write mapping (gate_global = tau*16 + ml), folded per group
    float bw[4];
    #pragma unroll
    for (int tau = 0; tau < 4; ++tau)
        bw[tau] = b_ih[tau * 16 + ml] + b_hh[tau * 16 + ml];

    // ---- recurrence-lane mapping: lane = u*4 + gate  (gate: 0=i,1=f,2=g,3=o) ----
    const int gate_t = lane & 3;
    const int u      = lane >> 2;
    const int grow   = gate_t * 16 + u;     // row in w_hh / b_*
    float whh[NH];
    #pragma unroll
    for (int j = 0; j < NH; j += 4) {
        float4 w4 = *(const float4*)(w_hh + grow * NH + j);
        whh[j] = w4.x; whh[j+1] = w4.y; whh[j+2] = w4.z; whh[j+3] = w4.w;
    }

    // unified activation: act = sA * sigma(sA*g) + sB  (tanh = 2*sigma(2x)-1)
    const bool  isg = (gate_t == 2);
    const float sA  = isg ? 2.f : 1.f;
    const float sB  = isg ? -1.f : 0.f;
    const float nk  = sA * -1.4426950408889634f;   // folded exp2 constant

    // ---- state (replicated across the 4 lanes of each cluster) ----
    float c_state = 0.f;
    float hs[NH];
    #pragma unroll
    for (int j = 0; j < NH; ++j) hs[j] = 0.f;
    float accfc[NCLS];
    #pragma unroll
    for (int cls = 0; cls < NCLS; ++cls) accfc[cls] = 0.f;

    // ---- prefetch first x group ----
    const float* xbase = x + ((size_t)b * SEQ + ml) * NIN + kk;
    float4 px0 = *(const float4*)(xbase + 0);
    float4 px1 = *(const float4*)(xbase + 4);
    float4 px2 = *(const float4*)(xbase + 32);
    float4 px3 = *(const float4*)(xbase + 36);

    for (int grp = 0; grp < SEQ / 16; ++grp) {
        // w_fc chunk for this group's FC partial (hoisted; latency hidden)
        float4 wf[NCLS];
        #pragma unroll
        for (int cls = 0; cls < NCLS; ++cls)
            wf[cls] = *(const float4*)(w_fc + cls * (SEQ * NH) + grp * 256 + lane * 4);

        // convert current group's x to MFMA A fragments (hi/lo)
        short8 a0h, a0l, a1h, a1l;
        split8(px0, px1, a0h, a0l);
        split8(px2, px3, a1h, a1l);

        // prefetch next group's x
        if (grp < SEQ / 16 - 1) {
            const float* xp = xbase + (size_t)(grp + 1) * 16 * NIN;
            px0 = *(const float4*)(xp + 0);
            px1 = *(const float4*)(xp + 4);
            px2 = *(const float4*)(xp + 32);
            px3 = *(const float4*)(xp + 36);
        }

        // gates_x for 16 timesteps: 4 gate tiles, K=64 in 2 chunks, hi/lo cross
        f32x4 acc[4];
        #pragma unroll
        for (int tau = 0; tau < 4; ++tau) {
            f32x4 c_ = {0.f, 0.f, 0.f, 0.f};
            c_ = __builtin_amdgcn_mfma_f32_16x16x32_bf16(a0h, Bh[tau][0], c_, 0, 0, 0);
            c_ = __builtin_amdgcn_mfma_f32_16x16x32_bf16(a1h, Bh[tau][1], c_, 0, 0, 0);
            c_ = __builtin_amdgcn_mfma_f32_16x16x32_bf16(a0l, Bh[tau][0], c_, 0, 0, 0);
            c_ = __builtin_amdgcn_mfma_f32_16x16x32_bf16(a0h, Bl[tau][0], c_, 0, 0, 0);
            c_ = __builtin_amdgcn_mfma_f32_16x16x32_bf16(a1l, Bh[tau][1], c_, 0, 0, 0);
            c_ = __builtin_amdgcn_mfma_f32_16x16x32_bf16(a1h, Bl[tau][1], c_, 0, 0, 0);
            acc[tau] = c_;
        }

        // scatter C to unit-major LDS rows (row = unit*4 + gate), bias folded
        #pragma unroll
        for (int tau = 0; tau < 4; ++tau) {
            f32x4 a4 = acc[tau];
            a4[0] += bw[tau]; a4[1] += bw[tau]; a4[2] += bw[tau]; a4[3] += bw[tau];
            *(f32x4*)&stageG[wid][(ml * 4 + tau) * GSTRIDE + half * 4] = a4;
        }
        __builtin_amdgcn_s_waitcnt(0xC07F);  // lgkmcnt(0) only; vmcnt untouched

        // each lane loads its own gate's 16-step row (vector, once per group)
        float gvv[16];
        #pragma unroll
        for (int q = 0; q < 4; ++q) {
            f32x4 g4 = *(f32x4*)&stageG[wid][lane * GSTRIDE + q * 4];
            gvv[q*4+0] = g4[0]; gvv[q*4+1] = g4[1]; gvv[q*4+2] = g4[2]; gvv[q*4+3] = g4[3];
        }

        // ---- 16 sequential recurrence steps (no memory/LDS-pipe on the chain) ----
        #pragma unroll
        for (int r = 0; r < 16; ++r) {
            float q0 = fmaf(hs[0], whh[0], gvv[r]);
            float q1 = hs[1] * whh[1];
            float q2 = hs[2] * whh[2];
            float q3 = hs[3] * whh[3];
            #pragma unroll
            for (int j = 4; j < NH; j += 4) {
                q0 = fmaf(hs[j+0], whh[j+0], q0);
                q1 = fmaf(hs[j+1], whh[j+1], q1);
                q2 = fmaf(hs[j+2], whh[j+2], q2);
                q3 = fmaf(hs[j+3], whh[j+3], q3);
            }
            const float gatev = (q0 + q1) + (q2 + q3);

            // activation (sigmoid for i,f,o; tanh for g) — sA folded into nk
            const float e   = __builtin_amdgcn_exp2f(gatev * nk);
            const float act = fmaf(sA, __builtin_amdgcn_rcpf(1.f + e), sB);

            // gather i,f,g,o within the 4-lane cluster via DPP quad_perm (VALU)
            const float ig = quad_bcast0(act);
            const float fg = quad_bcast1(act);
            const float gg = quad_bcast2(act);
            const float og = quad_bcast3(act);

            c_state = fmaf(fg, c_state, ig * gg);
            const float e2 = __builtin_amdgcn_exp2f(c_state * -2.8853900817779268f);
            const float th = fmaf(2.f, __builtin_amdgcn_rcpf(1.f + e2), -1.f);
            const float hn = og * th;

            if ((lane & 3) == 0) stageHT[wid][r * NH + u] = hn;

            // broadcast new h as wave-uniform scalars (SGPRs); h[j] lives on lane 4j
            #pragma unroll
            for (int j = 0; j < NH; ++j) hs[j] = readlane_f(hn, 4 * j);
        }
        __builtin_amdgcn_s_waitcnt(0xC07F);  // hist writes visible

        // ---- FC partial for this group: all 64 lanes, vector LDS read ----
        {
            float4 h4 = *(float4*)&stageHT[wid][lane * 4];
            #pragma unroll
            for (int cls = 0; cls < NCLS; ++cls) {
                accfc[cls] = fmaf(h4.x, wf[cls].x, accfc[cls]);
                accfc[cls] = fmaf(h4.y, wf[cls].y, accfc[cls]);
                accfc[cls] = fmaf(h4.z, wf[cls].z, accfc[cls]);
                accfc[cls] = fmaf(h4.w, wf[cls].w, accfc[cls]);
            }
        }
    }

    // ---- reduce FC accumulators over all 64 lanes and store ----
    #pragma unroll
    for (int cls = 0; cls < NCLS; ++cls) {
        float v = accfc[cls];
        v += __shfl_xor(v, 1);
        v += __shfl_xor(v, 2);
        v += __shfl_xor(v, 4);
        v += __shfl_xor(v, 8);
        v += __shfl_xor(v, 16);
        v += __shfl_xor(v, 32);
        accfc[cls] = v;
    }
    if (lane == 0) {
        #pragma unroll
        for (int cls = 0; cls < NCLS; ++cls)
            out[b * NCLS + cls] = accfc[cls] + b_fc[cls];
    }
}

extern "C" void kernel_launch(void* const* d_in, const int* in_sizes, int n_in,
                              void* d_out, int out_size, void* d_ws, size_t ws_size,
                              hipStream_t stream) {
    const float* x    = (const float*)d_in[0];
    const float* w_ih = (const float*)d_in[1];
    const float* w_hh = (const float*)d_in[2];
    const float* b_ih = (const float*)d_in[3];
    const float* b_hh = (const float*)d_in[4];
    const float* w_fc = (const float*)d_in[5];
    const float* b_fc = (const float*)d_in[6];
    float* out = (float*)d_out;

    hipLaunchKernelGGL(lstm_fused_kernel, dim3(NB / 4), dim3(256), 0, stream,
                       x, w_ih, w_hh, b_ih, b_hh, w_fc, b_fc, out);
}

// Round 5
// 238.784 us; speedup vs baseline: 1.6385x; 1.0016x over previous
//
#include <hip/hip_runtime.h>
#include <stdint.h>

#define SEQ   512
#define NB    1024
#define NIN   64
#define NH    16
#define NCLS  6
#define GSTRIDE 20   // floats per gate row in LDS (16 data + 4 pad)
#define NGRP  (SEQ / 16)

typedef __attribute__((ext_vector_type(8))) short short8;
typedef __attribute__((ext_vector_type(4))) float f32x4;

__device__ __forceinline__ float readlane_f(float v, int l) {
    return __int_as_float(__builtin_amdgcn_readlane(__float_as_int(v), l));
}

// Split fp32 -> bf16 hi + bf16 lo (truncation split; residual ~2^-16 relative)
__device__ __forceinline__ void split8(float4 u0, float4 u1, short8& hi, short8& lo) {
    float f[8] = {u0.x, u0.y, u0.z, u0.w, u1.x, u1.y, u1.z, u1.w};
    #pragma unroll
    for (int j = 0; j < 8; ++j) {
        uint32_t b = __float_as_uint(f[j]);
        uint16_t hb = (uint16_t)(b >> 16);
        hi[j] = (short)hb;
        float hf = __uint_as_float(((uint32_t)hb) << 16);
        lo[j] = (short)(uint16_t)(__float_as_uint(f[j] - hf) >> 16);
    }
}

// quad_perm broadcast via update_dpp (R4-verified on gfx950)
__device__ __forceinline__ float quad_bcast0(float v) {
    return __int_as_float(__builtin_amdgcn_update_dpp(0, __float_as_int(v), 0x00, 0xF, 0xF, true));
}
__device__ __forceinline__ float quad_bcast1(float v) {
    return __int_as_float(__builtin_amdgcn_update_dpp(0, __float_as_int(v), 0x55, 0xF, 0xF, true));
}
__device__ __forceinline__ float quad_bcast2(float v) {
    return __int_as_float(__builtin_amdgcn_update_dpp(0, __float_as_int(v), 0xAA, 0xF, 0xF, true));
}
__device__ __forceinline__ float quad_bcast3(float v) {
    return __int_as_float(__builtin_amdgcn_update_dpp(0, __float_as_int(v), 0xFF, 0xF, 0xF, true));
}

__global__ __launch_bounds__(512, 2)
void lstm_ws_kernel(const float* __restrict__ x,
                    const float* __restrict__ w_ih,
                    const float* __restrict__ w_hh,
                    const float* __restrict__ b_ih,
                    const float* __restrict__ b_hh,
                    const float* __restrict__ w_fc,
                    const float* __restrict__ b_fc,
                    float* __restrict__ out)
{
    // double-buffered gate stage + h-history, per batch element (4 per block)
    __shared__ float G [4][2][64 * GSTRIDE];   // 40 KB
    __shared__ float HT[4][2][16 * NH];        //  8 KB

    const int tid  = threadIdx.x;
    const int wid  = tid >> 6;       // 0..7
    const int lane = tid & 63;
    const int e    = wid & 3;        // batch element within block
    const int b    = blockIdx.x * 4 + e;
    const bool producer = (wid < 4);

    if (producer) {
        // ================= PRODUCER: x-GEMM + staging + FC =================
        const int ml   = lane & 15;      // MFMA A row (timestep) / B col
        const int half = lane >> 4;      // 0..3
        const int kk   = half * 8;

        // preload w_ih B fragments (4 gate tiles x 2 K-chunks, hi/lo split)
        short8 Bh[4][2], Bl[4][2];
        #pragma unroll
        for (int tau = 0; tau < 4; ++tau) {
            #pragma unroll
            for (int ch = 0; ch < 2; ++ch) {
                const float* wr = w_ih + (tau * 16 + ml) * NIN + ch * 32 + kk;
                float4 u0 = *(const float4*)wr;
                float4 u1 = *(const float4*)(wr + 4);
                split8(u0, u1, Bh[tau][ch], Bl[tau][ch]);
            }
        }
        // bias folded at scatter (gate_global = tau*16 + ml)
        float bw[4];
        #pragma unroll
        for (int tau = 0; tau < 4; ++tau)
            bw[tau] = b_ih[tau * 16 + ml] + b_hh[tau * 16 + ml];

        const float* xbase = x + ((size_t)b * SEQ + ml) * NIN + kk;
        float4 px0 = *(const float4*)(xbase + 0);
        float4 px1 = *(const float4*)(xbase + 4);
        float4 px2 = *(const float4*)(xbase + 32);
        float4 px3 = *(const float4*)(xbase + 36);

        // prologue: compute G[0]
        {
            short8 a0h, a0l, a1h, a1l;
            split8(px0, px1, a0h, a0l);
            split8(px2, px3, a1h, a1l);
            #pragma unroll
            for (int tau = 0; tau < 4; ++tau) {
                f32x4 c_ = {0.f, 0.f, 0.f, 0.f};
                c_ = __builtin_amdgcn_mfma_f32_16x16x32_bf16(a0h, Bh[tau][0], c_, 0, 0, 0);
                c_ = __builtin_amdgcn_mfma_f32_16x16x32_bf16(a1h, Bh[tau][1], c_, 0, 0, 0);
                c_ = __builtin_amdgcn_mfma_f32_16x16x32_bf16(a0l, Bh[tau][0], c_, 0, 0, 0);
                c_ = __builtin_amdgcn_mfma_f32_16x16x32_bf16(a0h, Bl[tau][0], c_, 0, 0, 0);
                c_ = __builtin_amdgcn_mfma_f32_16x16x32_bf16(a1l, Bh[tau][1], c_, 0, 0, 0);
                c_ = __builtin_amdgcn_mfma_f32_16x16x32_bf16(a1h, Bl[tau][1], c_, 0, 0, 0);
                c_[0] += bw[tau]; c_[1] += bw[tau]; c_[2] += bw[tau]; c_[3] += bw[tau];
                *(f32x4*)&G[e][0][(ml * 4 + tau) * GSTRIDE + half * 4] = c_;
            }
        }
        // prefetch group 1
        {
            const float* xp = xbase + (size_t)16 * NIN;
            px0 = *(const float4*)(xp + 0);
            px1 = *(const float4*)(xp + 4);
            px2 = *(const float4*)(xp + 32);
            px3 = *(const float4*)(xp + 36);
        }
        __syncthreads();   // barrier 0: G[0] ready

        float accfc[NCLS];
        #pragma unroll
        for (int cls = 0; cls < NCLS; ++cls) accfc[cls] = 0.f;

        for (int g = 0; g < NGRP; ++g) {
            if (g < NGRP - 1) {
                // stage gates for group g+1 into buffer (g+1)&1
                short8 a0h, a0l, a1h, a1l;
                split8(px0, px1, a0h, a0l);
                split8(px2, px3, a1h, a1l);
                if (g < NGRP - 2) {
                    const float* xp = xbase + (size_t)(g + 2) * 16 * NIN;
                    px0 = *(const float4*)(xp + 0);
                    px1 = *(const float4*)(xp + 4);
                    px2 = *(const float4*)(xp + 32);
                    px3 = *(const float4*)(xp + 36);
                }
                #pragma unroll
                for (int tau = 0; tau < 4; ++tau) {
                    f32x4 c_ = {0.f, 0.f, 0.f, 0.f};
                    c_ = __builtin_amdgcn_mfma_f32_16x16x32_bf16(a0h, Bh[tau][0], c_, 0, 0, 0);
                    c_ = __builtin_amdgcn_mfma_f32_16x16x32_bf16(a1h, Bh[tau][1], c_, 0, 0, 0);
                    c_ = __builtin_amdgcn_mfma_f32_16x16x32_bf16(a0l, Bh[tau][0], c_, 0, 0, 0);
                    c_ = __builtin_amdgcn_mfma_f32_16x16x32_bf16(a0h, Bl[tau][0], c_, 0, 0, 0);
                    c_ = __builtin_amdgcn_mfma_f32_16x16x32_bf16(a1l, Bh[tau][1], c_, 0, 0, 0);
                    c_ = __builtin_amdgcn_mfma_f32_16x16x32_bf16(a1h, Bl[tau][1], c_, 0, 0, 0);
                    c_[0] += bw[tau]; c_[1] += bw[tau]; c_[2] += bw[tau]; c_[3] += bw[tau];
                    *(f32x4*)&G[e][(g + 1) & 1][(ml * 4 + tau) * GSTRIDE + half * 4] = c_;
                }
            }
            if (g > 0) {
                // FC partial for group g-1 from HT[(g-1)&1]
                const int gp = g - 1;
                float4 h4 = *(float4*)&HT[e][gp & 1][lane * 4];
                #pragma unroll
                for (int cls = 0; cls < NCLS; ++cls) {
                    float4 wf = *(const float4*)(w_fc + cls * (SEQ * NH) + gp * 256 + lane * 4);
                    accfc[cls] = fmaf(h4.x, wf.x, accfc[cls]);
                    accfc[cls] = fmaf(h4.y, wf.y, accfc[cls]);
                    accfc[cls] = fmaf(h4.z, wf.z, accfc[cls]);
                    accfc[cls] = fmaf(h4.w, wf.w, accfc[cls]);
                }
            }
            __syncthreads();   // barrier g+1: G[(g+1)&1] ready, HT[g&1] ready
        }

        // epilogue: FC for group 31
        {
            const int gp = NGRP - 1;
            float4 h4 = *(float4*)&HT[e][gp & 1][lane * 4];
            #pragma unroll
            for (int cls = 0; cls < NCLS; ++cls) {
                float4 wf = *(const float4*)(w_fc + cls * (SEQ * NH) + gp * 256 + lane * 4);
                accfc[cls] = fmaf(h4.x, wf.x, accfc[cls]);
                accfc[cls] = fmaf(h4.y, wf.y, accfc[cls]);
                accfc[cls] = fmaf(h4.z, wf.z, accfc[cls]);
                accfc[cls] = fmaf(h4.w, wf.w, accfc[cls]);
            }
        }
        #pragma unroll
        for (int cls = 0; cls < NCLS; ++cls) {
            float v = accfc[cls];
            v += __shfl_xor(v, 1);
            v += __shfl_xor(v, 2);
            v += __shfl_xor(v, 4);
            v += __shfl_xor(v, 8);
            v += __shfl_xor(v, 16);
            v += __shfl_xor(v, 32);
            accfc[cls] = v;
        }
        if (lane == 0) {
            #pragma unroll
            for (int cls = 0; cls < NCLS; ++cls)
                out[b * NCLS + cls] = accfc[cls] + b_fc[cls];
        }
    } else {
        // ================= CONSUMER: pure recurrence chain =================
        // lane = u*4 + gate  (gate: 0=i,1=f,2=g,3=o)
        const int gate_t = lane & 3;
        const int u      = lane >> 2;
        const int grow   = gate_t * 16 + u;
        float whh[NH];
        #pragma unroll
        for (int j = 0; j < NH; j += 4) {
            float4 w4 = *(const float4*)(w_hh + grow * NH + j);
            whh[j] = w4.x; whh[j+1] = w4.y; whh[j+2] = w4.z; whh[j+3] = w4.w;
        }
        const bool  isg = (gate_t == 2);
        const float sA  = isg ? 2.f : 1.f;
        const float sB  = isg ? -1.f : 0.f;
        const float nk  = sA * -1.4426950408889634f;

        float c_state = 0.f;
        float hs[NH];
        #pragma unroll
        for (int j = 0; j < NH; ++j) hs[j] = 0.f;

        __syncthreads();   // barrier 0: G[0] ready

        for (int g = 0; g < NGRP; ++g) {
            // this lane's gate row for 16 steps (vector LDS read, off-chain)
            float gvv[16];
            #pragma unroll
            for (int q = 0; q < 4; ++q) {
                f32x4 g4 = *(f32x4*)&G[e][g & 1][lane * GSTRIDE + q * 4];
                gvv[q*4+0] = g4[0]; gvv[q*4+1] = g4[1]; gvv[q*4+2] = g4[2]; gvv[q*4+3] = g4[3];
            }

            #pragma unroll
            for (int r = 0; r < 16; ++r) {
                float q0 = fmaf(hs[0], whh[0], gvv[r]);
                float q1 = hs[1] * whh[1];
                float q2 = hs[2] * whh[2];
                float q3 = hs[3] * whh[3];
                #pragma unroll
                for (int j = 4; j < NH; j += 4) {
                    q0 = fmaf(hs[j+0], whh[j+0], q0);
                    q1 = fmaf(hs[j+1], whh[j+1], q1);
                    q2 = fmaf(hs[j+2], whh[j+2], q2);
                    q3 = fmaf(hs[j+3], whh[j+3], q3);
                }
                const float gatev = (q0 + q1) + (q2 + q3);

                const float ex  = __builtin_amdgcn_exp2f(gatev * nk);
                const float act = fmaf(sA, __builtin_amdgcn_rcpf(1.f + ex), sB);

                const float ig = quad_bcast0(act);
                const float fg = quad_bcast1(act);
                const float gg = quad_bcast2(act);
                const float og = quad_bcast3(act);

                c_state = fmaf(fg, c_state, ig * gg);
                const float e2 = __builtin_amdgcn_exp2f(c_state * -2.8853900817779268f);
                const float th = fmaf(2.f, __builtin_amdgcn_rcpf(1.f + e2), -1.f);
                const float hn = og * th;

                // all 4 cluster lanes write the same value (no exec-mask dance)
                HT[e][g & 1][r * NH + u] = hn;

                #pragma unroll
                for (int j = 0; j < NH; ++j) hs[j] = readlane_f(hn, 4 * j);
            }
            __syncthreads();   // barrier g+1
        }
        // no epilogue work for consumers
    }
}

extern "C" void kernel_launch(void* const* d_in, const int* in_sizes, int n_in,
                              void* d_out, int out_size, void* d_ws, size_t ws_size,
                              hipStream_t stream) {
    const float* x    = (const float*)d_in[0];
    const float* w_ih = (const float*)d_in[1];
    const float* w_hh = (const float*)d_in[2];
    const float* b_ih = (const float*)d_in[3];
    const float* b_hh = (const float*)d_in[4];
    const float* w_fc = (const float*)d_in[5];
    const float* b_fc = (const float*)d_in[6];
    float* out = (float*)d_out;

    hipLaunchKernelGGL(lstm_ws_kernel, dim3(NB / 4), dim3(512), 0, stream,
                       x, w_ih, w_hh, b_ih, b_hh, w_fc, b_fc, out);
}

// Round 6
// 238.231 us; speedup vs baseline: 1.6423x; 1.0023x over previous
//
#include <hip/hip_runtime.h>
#include <stdint.h>

#define SEQ   512
#define NB    1024
#define NIN   64
#define NH    16
#define NCLS  6
#define GSTRIDE 20   // floats per gate row in LDS (16 data + 4 pad)
#define NGRP  (SEQ / 16)

typedef __attribute__((ext_vector_type(8))) short short8;
typedef __attribute__((ext_vector_type(4))) float f32x4;

// constants: gate pre-acts are pre-scaled so exp2 consumes them directly.
// i,f,o: z' = -log2e * z      -> sigma(z)  = rcp(1+exp2(z'))
// g:     z' = -2*log2e * z    -> sigma(2z) = rcp(1+exp2(z')); tanh(z)=2r-1
// c kept pre-scaled by K = -2*log2e (so exp2(C) = e^{-2c}); g-lane output
// constants fold K: act_g = K*tanh(g) = 2K*r - K.
#define LOG2E   1.4426950408889634f
#define NK_IFO  (-1.4426950408889634f)
#define NK_G    (-2.8853900817779268f)
#define KC      (-2.8853900817779268f)

__device__ __forceinline__ float readlane_f(float v, int l) {
    return __int_as_float(__builtin_amdgcn_readlane(__float_as_int(v), l));
}

// Split fp32 -> bf16 hi + bf16 lo (truncation split; residual ~2^-16 relative)
__device__ __forceinline__ void split8(float4 u0, float4 u1, short8& hi, short8& lo) {
    float f[8] = {u0.x, u0.y, u0.z, u0.w, u1.x, u1.y, u1.z, u1.w};
    #pragma unroll
    for (int j = 0; j < 8; ++j) {
        uint32_t b = __float_as_uint(f[j]);
        uint16_t hb = (uint16_t)(b >> 16);
        hi[j] = (short)hb;
        float hf = __uint_as_float(((uint32_t)hb) << 16);
        lo[j] = (short)(uint16_t)(__float_as_uint(f[j] - hf) >> 16);
    }
}

// quad_perm broadcast via update_dpp (R4/R5-verified on gfx950)
__device__ __forceinline__ float quad_bcast0(float v) {
    return __int_as_float(__builtin_amdgcn_update_dpp(0, __float_as_int(v), 0x00, 0xF, 0xF, true));
}
__device__ __forceinline__ float quad_bcast1(float v) {
    return __int_as_float(__builtin_amdgcn_update_dpp(0, __float_as_int(v), 0x55, 0xF, 0xF, true));
}
__device__ __forceinline__ float quad_bcast2(float v) {
    return __int_as_float(__builtin_amdgcn_update_dpp(0, __float_as_int(v), 0xAA, 0xF, 0xF, true));
}
__device__ __forceinline__ float quad_bcast3(float v) {
    return __int_as_float(__builtin_amdgcn_update_dpp(0, __float_as_int(v), 0xFF, 0xF, 0xF, true));
}

__global__ __launch_bounds__(512, 2)
void lstm_ws_kernel(const float* __restrict__ x,
                    const float* __restrict__ w_ih,
                    const float* __restrict__ w_hh,
                    const float* __restrict__ b_ih,
                    const float* __restrict__ b_hh,
                    const float* __restrict__ w_fc,
                    const float* __restrict__ b_fc,
                    float* __restrict__ out)
{
    __shared__ float G [4][2][64 * GSTRIDE];   // 40 KB, pre-scaled gates
    __shared__ float HT[4][2][16 * NH];        //  8 KB, h history

    const int tid  = threadIdx.x;
    const int wid  = tid >> 6;       // 0..7
    const int lane = tid & 63;
    const int e    = wid & 3;        // batch element within block
    const int b    = blockIdx.x * 4 + e;
    const bool producer = (wid < 4);

    if (producer) {
        // ================= PRODUCER: x-GEMM + staging + FC =================
        const int ml   = lane & 15;      // MFMA A row (timestep) / B col
        const int half = lane >> 4;      // 0..3
        const int kk   = half * 8;

        short8 Bh[4][2], Bl[4][2];
        #pragma unroll
        for (int tau = 0; tau < 4; ++tau) {
            #pragma unroll
            for (int ch = 0; ch < 2; ++ch) {
                const float* wr = w_ih + (tau * 16 + ml) * NIN + ch * 32 + kk;
                float4 u0 = *(const float4*)wr;
                float4 u1 = *(const float4*)(wr + 4);
                split8(u0, u1, Bh[tau][ch], Bl[tau][ch]);
            }
        }
        // per-tile exp2 prescale + prescaled bias (gate row = tau*16 + ml; tau==2 is g)
        float nkt[4], bwk[4];
        #pragma unroll
        for (int tau = 0; tau < 4; ++tau) {
            nkt[tau] = (tau == 2) ? NK_G : NK_IFO;
            bwk[tau] = (b_ih[tau * 16 + ml] + b_hh[tau * 16 + ml]) * nkt[tau];
        }

        const float* xbase = x + ((size_t)b * SEQ + ml) * NIN + kk;
        float4 px0 = *(const float4*)(xbase + 0);
        float4 px1 = *(const float4*)(xbase + 4);
        float4 px2 = *(const float4*)(xbase + 32);
        float4 px3 = *(const float4*)(xbase + 36);

        // prologue: compute G[0]
        {
            short8 a0h, a0l, a1h, a1l;
            split8(px0, px1, a0h, a0l);
            split8(px2, px3, a1h, a1l);
            #pragma unroll
            for (int tau = 0; tau < 4; ++tau) {
                f32x4 c_ = {0.f, 0.f, 0.f, 0.f};
                c_ = __builtin_amdgcn_mfma_f32_16x16x32_bf16(a0h, Bh[tau][0], c_, 0, 0, 0);
                c_ = __builtin_amdgcn_mfma_f32_16x16x32_bf16(a1h, Bh[tau][1], c_, 0, 0, 0);
                c_ = __builtin_amdgcn_mfma_f32_16x16x32_bf16(a0l, Bh[tau][0], c_, 0, 0, 0);
                c_ = __builtin_amdgcn_mfma_f32_16x16x32_bf16(a0h, Bl[tau][0], c_, 0, 0, 0);
                c_ = __builtin_amdgcn_mfma_f32_16x16x32_bf16(a1l, Bh[tau][1], c_, 0, 0, 0);
                c_ = __builtin_amdgcn_mfma_f32_16x16x32_bf16(a1h, Bl[tau][1], c_, 0, 0, 0);
                f32x4 s_;
                s_[0] = fmaf(c_[0], nkt[tau], bwk[tau]);
                s_[1] = fmaf(c_[1], nkt[tau], bwk[tau]);
                s_[2] = fmaf(c_[2], nkt[tau], bwk[tau]);
                s_[3] = fmaf(c_[3], nkt[tau], bwk[tau]);
                *(f32x4*)&G[e][0][(ml * 4 + tau) * GSTRIDE + half * 4] = s_;
            }
        }
        {
            const float* xp = xbase + (size_t)16 * NIN;
            px0 = *(const float4*)(xp + 0);
            px1 = *(const float4*)(xp + 4);
            px2 = *(const float4*)(xp + 32);
            px3 = *(const float4*)(xp + 36);
        }
        __syncthreads();   // barrier 0: G[0] ready

        float accfc[NCLS];
        #pragma unroll
        for (int cls = 0; cls < NCLS; ++cls) accfc[cls] = 0.f;

        for (int g = 0; g < NGRP; ++g) {
            if (g < NGRP - 1) {
                short8 a0h, a0l, a1h, a1l;
                split8(px0, px1, a0h, a0l);
                split8(px2, px3, a1h, a1l);
                if (g < NGRP - 2) {
                    const float* xp = xbase + (size_t)(g + 2) * 16 * NIN;
                    px0 = *(const float4*)(xp + 0);
                    px1 = *(const float4*)(xp + 4);
                    px2 = *(const float4*)(xp + 32);
                    px3 = *(const float4*)(xp + 36);
                }
                #pragma unroll
                for (int tau = 0; tau < 4; ++tau) {
                    f32x4 c_ = {0.f, 0.f, 0.f, 0.f};
                    c_ = __builtin_amdgcn_mfma_f32_16x16x32_bf16(a0h, Bh[tau][0], c_, 0, 0, 0);
                    c_ = __builtin_amdgcn_mfma_f32_16x16x32_bf16(a1h, Bh[tau][1], c_, 0, 0, 0);
                    c_ = __builtin_amdgcn_mfma_f32_16x16x32_bf16(a0l, Bh[tau][0], c_, 0, 0, 0);
                    c_ = __builtin_amdgcn_mfma_f32_16x16x32_bf16(a0h, Bl[tau][0], c_, 0, 0, 0);
                    c_ = __builtin_amdgcn_mfma_f32_16x16x32_bf16(a1l, Bh[tau][1], c_, 0, 0, 0);
                    c_ = __builtin_amdgcn_mfma_f32_16x16x32_bf16(a1h, Bl[tau][1], c_, 0, 0, 0);
                    f32x4 s_;
                    s_[0] = fmaf(c_[0], nkt[tau], bwk[tau]);
                    s_[1] = fmaf(c_[1], nkt[tau], bwk[tau]);
                    s_[2] = fmaf(c_[2], nkt[tau], bwk[tau]);
                    s_[3] = fmaf(c_[3], nkt[tau], bwk[tau]);
                    *(f32x4*)&G[e][(g + 1) & 1][(ml * 4 + tau) * GSTRIDE + half * 4] = s_;
                }
            }
            if (g > 0) {
                const int gp = g - 1;
                float4 h4 = *(float4*)&HT[e][gp & 1][lane * 4];
                #pragma unroll
                for (int cls = 0; cls < NCLS; ++cls) {
                    float4 wf = *(const float4*)(w_fc + cls * (SEQ * NH) + gp * 256 + lane * 4);
                    accfc[cls] = fmaf(h4.x, wf.x, accfc[cls]);
                    accfc[cls] = fmaf(h4.y, wf.y, accfc[cls]);
                    accfc[cls] = fmaf(h4.z, wf.z, accfc[cls]);
                    accfc[cls] = fmaf(h4.w, wf.w, accfc[cls]);
                }
            }
            __syncthreads();   // barrier g+1
        }
        {
            const int gp = NGRP - 1;
            float4 h4 = *(float4*)&HT[e][gp & 1][lane * 4];
            #pragma unroll
            for (int cls = 0; cls < NCLS; ++cls) {
                float4 wf = *(const float4*)(w_fc + cls * (SEQ * NH) + gp * 256 + lane * 4);
                accfc[cls] = fmaf(h4.x, wf.x, accfc[cls]);
                accfc[cls] = fmaf(h4.y, wf.y, accfc[cls]);
                accfc[cls] = fmaf(h4.z, wf.z, accfc[cls]);
                accfc[cls] = fmaf(h4.w, wf.w, accfc[cls]);
            }
        }
        #pragma unroll
        for (int cls = 0; cls < NCLS; ++cls) {
            float v = accfc[cls];
            v += __shfl_xor(v, 1);
            v += __shfl_xor(v, 2);
            v += __shfl_xor(v, 4);
            v += __shfl_xor(v, 8);
            v += __shfl_xor(v, 16);
            v += __shfl_xor(v, 32);
            accfc[cls] = v;
        }
        if (lane == 0) {
            #pragma unroll
            for (int cls = 0; cls < NCLS; ++cls)
                out[b * NCLS + cls] = accfc[cls] + b_fc[cls];
        }
    } else {
        // ================= CONSUMER: pure recurrence chain =================
        // lane = u*4 + gate  (gate: 0=i,1=f,2=g,3=o)
        const int gate_t = lane & 3;
        const int u      = lane >> 2;
        const int grow   = gate_t * 16 + u;
        const float nkl  = (gate_t == 2) ? NK_G : NK_IFO;    // matches producer prescale
        float whh[NH];
        #pragma unroll
        for (int j = 0; j < NH; j += 4) {
            float4 w4 = *(const float4*)(w_hh + grow * NH + j);
            whh[j]   = w4.x * nkl;
            whh[j+1] = w4.y * nkl;
            whh[j+2] = w4.z * nkl;
            whh[j+3] = w4.w * nkl;
        }
        // output constants: i,f,o -> sigma; g -> K*tanh  (K folded so C is pre-scaled)
        const bool  isg = (gate_t == 2);
        const float sO  = isg ? (2.f * KC) : 1.f;
        const float sB  = isg ? (-KC)      : 0.f;

        float C = 0.f;                 // pre-scaled cell state: C = K * c
        float hs[NH];
        #pragma unroll
        for (int j = 0; j < NH; ++j) hs[j] = 0.f;

        __syncthreads();   // barrier 0: G[0] ready

        for (int g = 0; g < NGRP; ++g) {
            float gvv[16];
            #pragma unroll
            for (int q = 0; q < 4; ++q) {
                f32x4 g4 = *(f32x4*)&G[e][g & 1][lane * GSTRIDE + q * 4];
                gvv[q*4+0] = g4[0]; gvv[q*4+1] = g4[1]; gvv[q*4+2] = g4[2]; gvv[q*4+3] = g4[3];
            }

            float hstore[16];

            #pragma unroll
            for (int r = 0; r < 16; ++r) {
                // matvec: z' = gvv' + (whh*nk)·h   (already exp2-prescaled)
                float q0 = fmaf(hs[0], whh[0], gvv[r]);
                float q1 = hs[1] * whh[1];
                float q2 = hs[2] * whh[2];
                float q3 = hs[3] * whh[3];
                #pragma unroll
                for (int j = 4; j < NH; j += 4) {
                    q0 = fmaf(hs[j+0], whh[j+0], q0);
                    q1 = fmaf(hs[j+1], whh[j+1], q1);
                    q2 = fmaf(hs[j+2], whh[j+2], q2);
                    q3 = fmaf(hs[j+3], whh[j+3], q3);
                }
                const float zp = (q0 + q1) + (q2 + q3);

                // act: i,f,o -> sigma(z); g -> K*tanh(z)   (exp2 arg pre-scaled)
                const float ex  = __builtin_amdgcn_exp2f(zp);
                const float act = fmaf(sO, __builtin_amdgcn_rcpf(1.f + ex), sB);

                // gather within 4-lane cluster (VALU DPP)
                const float ig = quad_bcast0(act);
                const float fg = quad_bcast1(act);
                const float gg = quad_bcast2(act);   // = K*tanh(g)
                const float og = quad_bcast3(act);

                // off-chain helpers during the exp2 latency
                const float igg = ig * gg;           // K * i * tanh(g)
                const float t2o = og + og;
                const float nog = -og;

                // pre-scaled cell update: C = f*C + K*i*tanh(g)  (C = K*c)
                C = fmaf(fg, C, igg);
                // h = o * tanh(c) = 2*o*rcp(1+e^{-2c}) - o ; exp2(C) = e^{-2c}
                const float e2 = __builtin_amdgcn_exp2f(C);
                const float r2 = __builtin_amdgcn_rcpf(1.f + e2);
                const float hn = fmaf(t2o, r2, nog);

                hstore[r] = hn;

                #pragma unroll
                for (int j = 0; j < NH; ++j) hs[j] = readlane_f(hn, 4 * j);
            }

            // batch h history to LDS (off-chain; all cluster lanes write same value)
            #pragma unroll
            for (int r = 0; r < 16; ++r)
                HT[e][g & 1][r * NH + u] = hstore[r];

            __syncthreads();   // barrier g+1
        }
    }
}

extern "C" void kernel_launch(void* const* d_in, const int* in_sizes, int n_in,
                              void* d_out, int out_size, void* d_ws, size_t ws_size,
                              hipStream_t stream) {
    const float* x    = (const float*)d_in[0];
    const float* w_ih = (const float*)d_in[1];
    const float* w_hh = (const float*)d_in[2];
    const float* b_ih = (const float*)d_in[3];
    const float* b_hh = (const float*)d_in[4];
    const float* w_fc = (const float*)d_in[5];
    const float* b_fc = (const float*)d_in[6];
    float* out = (float*)d_out;

    hipLaunchKernelGGL(lstm_ws_kernel, dim3(NB / 4), dim3(512), 0, stream,
                       x, w_ih, w_hh, b_ih, b_hh, w_fc, b_fc, out);
}